// Round 16
// baseline (1283.085 us; speedup 1.0000x reference)
//
#include <hip/hip_runtime.h>
#include <math.h>

#define NS 512
#define NE 2048
#define NB 64
#define NT 512
#define SENT 0x7FC0DEADu  // NaN payload; real v values are always finite

// out[c][r] = in[r][c]; rows, cols multiples of 32
__global__ __launch_bounds__(256) void transpose_k(const float* __restrict__ in,
                                                   float* __restrict__ out,
                                                   int rows, int cols) {
  __shared__ float tile[32][33];
  int c0 = blockIdx.x * 32;
  int r0 = blockIdx.y * 32;
  int tx = threadIdx.x;  // 0..31
  int ty = threadIdx.y;  // 0..7
#pragma unroll
  for (int k = 0; k < 32; k += 8) {
    tile[ty + k][tx] = in[(size_t)(r0 + ty + k) * cols + (c0 + tx)];
  }
  __syncthreads();
#pragma unroll
  for (int k = 0; k < 32; k += 8) {
    out[(size_t)(c0 + ty + k) * rows + (r0 + tx)] = tile[tx][ty + k];
  }
}

// Pre-fill v[1..NT) with the sentinel each call (slots write-once per call;
// harness does not re-poison between replays).
__global__ __launch_bounds__(256) void fill_sentinel(float* __restrict__ v) {
  uint4 s = make_uint4(SENT, SENT, SENT, SENT);
  uint4* p = reinterpret_cast<uint4*>(v + (size_t)NB * NS);
  const size_t n4 = (size_t)(NT - 1) * NB * NS / 4;
  for (size_t i = (size_t)blockIdx.x * blockDim.x + threadIdx.x; i < n4;
       i += (size_t)gridDim.x * blockDim.x)
    p[i] = s;
}

// Forward, dataflow column-slice with backpointer emission. Grid 512 = 64
// groups x 8 members (bid = g + 64*m). Member m owns columns [64m,64m+64).
// Wave oct owns i-block p=(m+oct)&7 ENTIRELY: thread (oct,jl) reduces column
// j=64m+jl over 64 contiguous ascending i -> strict-> tournament = exact
// first-wins argmax in-loop (~4 VALU/score, hidden in the 1.4us chain slack
// R14/R15 measured). Per-wave gather: wave oct fetches exactly the slice it
// consumes (sentinel retry, R14 protocol) -> NO cross-wave gather barrier;
// waves unblock independently as remote slices land. parts parity-buffered
// (safe: part(t+2) writes are ordered after E(t) reads via the publish->
// gather dependency chain) -> SINGLE __syncthreads per iteration.
// E (wave0, post-barrier): 7-way first-wins merge + emission, publish v[t]
// (atomic, exchange medium) + bp[t] (ushort, plain store, read only by bt).
__global__ __launch_bounds__(512) void viterbi_fwd(
    const int* __restrict__ obs,     // [NB][NT]
    const float* __restrict__ start, // [NS]
    const float* __restrict__ trans, // [NS][NS]
    const float* __restrict__ emT,   // [NE][NS]
    float* __restrict__ v,           // [NT][NB][NS] exchange + final row
    unsigned short* __restrict__ bp) // [NB][NT][NS] backpointers
{
  const int g = blockIdx.x & 63;
  const int m = blockIdx.x >> 6;       // member 0..7
  const int tid = threadIdx.x;
  const int jl = tid & 63;
  const int oct = tid >> 6;            // wave 0..7
  const int j = m * 64 + jl;           // my output column
  const int p = (m + oct) & 7;         // i-block this wave covers
  const int i0 = p * 64;

  __shared__ __align__(16) float vf[NS];
  __shared__ float part_v[2][8][64];
  __shared__ int part_i[2][8][64];
  __shared__ int obs_s[NT];

  obs_s[tid] = obs[g * NT + tid];
  // t = 0: full v0 in LDS (all threads); v[0] is never read -> no checkpoint.
  {
    int o0 = obs[g * NT];
    vf[tid] = start[tid] + emT[(size_t)o0 * NS + tid];
  }
  __syncthreads();

  for (int t = 1; t < NT; ++t) {
    const int par = t & 1;
    float e = 0.f;
    if (oct == 0) e = emT[(size_t)obs_s[t] * NS + j];  // prefetch for E

    // ---- per-wave gather of exactly my slice (sentinel retry) ----
    if (t >= 2 && oct != 0) {
      const float* ap = v + ((size_t)(t - 1) * NB + g) * NS + i0 + jl;
      float ga = __hip_atomic_load(ap, __ATOMIC_RELAXED, __HIP_MEMORY_SCOPE_AGENT);
      while (__any(__float_as_uint(ga) == SENT)) {
        __builtin_amdgcn_s_sleep(1);
        ga = __hip_atomic_load(ap, __ATOMIC_RELAXED, __HIP_MEMORY_SCOPE_AGENT);
      }
      vf[i0 + jl] = ga;  // consumed only by this wave (ds-order within wave)
    }
    // wave0: vf[own block] was written by its own E(t-1) — same wave, ready.

    // ---- compute block p for column j, i ascending: first-wins argmax ----
    float bv = -INFINITY;
    int bi = 0;
    {
      const float* tp = trans + (size_t)i0 * NS + j;
      const float4* va = reinterpret_cast<const float4*>(vf + i0);
#pragma unroll
      for (int c = 0; c < 16; ++c) {
        float4 x = va[c];
        float s0 = x.x + tp[(size_t)(4 * c + 0) * NS];
        float s1 = x.y + tp[(size_t)(4 * c + 1) * NS];
        float s2 = x.z + tp[(size_t)(4 * c + 2) * NS];
        float s3 = x.w + tp[(size_t)(4 * c + 3) * NS];
        if (s0 > bv) { bv = s0; bi = 4 * c + 0; }  // ascending i, strict >
        if (s1 > bv) { bv = s1; bi = 4 * c + 1; }
        if (s2 > bv) { bv = s2; bi = 4 * c + 2; }
        if (s3 > bv) { bv = s3; bi = 4 * c + 3; }
      }
    }
    if (oct != 0) {  // wave0 keeps its own partial in registers
      part_v[par][oct][jl] = bv;
      part_i[par][oct][jl] = i0 + bi;
    }
    __syncthreads();  // the ONE barrier: parts(t) ready for E(t)

    // ---- E: wave0 merges 8 partials (first-wins), publishes v[t] + bp[t] ----
    if (oct == 0) {
      float mv = bv;
      int mi = i0 + bi;  // own block (p == m)
#pragma unroll
      for (int o = 1; o < 8; ++o) {
        float pv = part_v[par][o][jl];
        int pi = part_i[par][o][jl];
        bool u = (pv > mv) || (pv == mv && pi < mi);
        mv = u ? pv : mv;
        mi = u ? pi : mi;
      }
      float vn = mv + e;
      vf[j] = vn;  // own block for next iter's wave0 compute
      bp[((size_t)g * NT + t) * NS + j] = (unsigned short)mi;
      __hip_atomic_store(v + ((size_t)t * NB + g) * NS + j, vn,
                         __ATOMIC_RELAXED, __HIP_MEMORY_SCOPE_AGENT);
    }
  }
}

// Backtrace: warm the batch's bp block into L2, final argmax (first-wins),
// then lane0 pointer-chases 511 dependent ushort loads (L2-hit ~220cy each).
__global__ __launch_bounds__(64) void viterbi_bt(
    const float* __restrict__ v,           // [NT][NB][NS] (final row used)
    const unsigned short* __restrict__ bp, // [NB][NT][NS]
    int* __restrict__ path)                // [NB][NT] int32
{
  const int b = blockIdx.x;
  const int lane = threadIdx.x;

  // warm this batch's 512KB bp block into L2 (keep-alive asm, rule #17)
  {
    const uint4* w = reinterpret_cast<const uint4*>(bp + (size_t)b * NT * NS);
    const int n = NT * NS / 8;  // uint4 count
#pragma unroll 4
    for (int i = lane; i < n; i += 64) {
      uint4 x = w[i];
      asm volatile("" ::"v"(x.x), "v"(x.y), "v"(x.z), "v"(x.w));
    }
  }

  // final argmax over v[NT-1][b][:], first-wins (lane covers [8l, 8l+8))
  const float4* vr = reinterpret_cast<const float4*>(v + ((size_t)(NT - 1) * NB + b) * NS);
  float4 a = vr[2 * lane];
  float4 c = vr[2 * lane + 1];
  float s0 = a.x, s1 = a.y, s2 = a.z, s3 = a.w;
  float s4 = c.x, s5 = c.y, s6 = c.z, s7 = c.w;
  float lm = fmaxf(fmaxf(fmaxf(s0, s1), fmaxf(s2, s3)),
                   fmaxf(fmaxf(s4, s5), fmaxf(s6, s7)));
  float M = lm;
#pragma unroll
  for (int off = 1; off < 64; off <<= 1) M = fmaxf(M, __shfl_xor(M, off));
  int k = 7;
  if (s6 == M) k = 6;
  if (s5 == M) k = 5;
  if (s4 == M) k = 4;
  if (s3 == M) k = 3;
  if (s2 == M) k = 2;
  if (s1 == M) k = 1;
  if (s0 == M) k = 0;
  unsigned long long bal = __ballot(lm == M);
  int first = __ffsll(bal) - 1;
  int state = __shfl(8 * lane + k, first);

  if (lane == 0) {
    path[b * NT + (NT - 1)] = state;
    const unsigned short* bpb = bp + (size_t)b * NT * NS;
    for (int t = NT - 1; t >= 1; --t) {
      state = bpb[(size_t)t * NS + state];
      path[b * NT + (t - 1)] = state;
    }
  }
}

extern "C" void kernel_launch(void* const* d_in, const int* in_sizes, int n_in,
                              void* d_out, int out_size, void* d_ws, size_t ws_size,
                              hipStream_t stream) {
  const int* obs = (const int*)d_in[0];       // [64][512]
  const float* start = (const float*)d_in[1]; // [512]
  const float* trans = (const float*)d_in[2]; // [512][512]
  const float* emis = (const float*)d_in[3];  // [512][2048]
  int* path = (int*)d_out;                    // [64][512] int32

  char* ws = (char*)d_ws;
  float* emT = (float*)ws;                              // [2048][512] = 4 MB
  float* v = (float*)(ws + (4ull << 20));               // [512][64][512] = 64 MB
  unsigned short* bp = (unsigned short*)(ws + (68ull << 20));  // [64][512][512] u16 = 32 MB

  fill_sentinel<<<1024, 256, 0, stream>>>(v);

  dim3 tb(32, 8);
  transpose_k<<<dim3(NE / 32, NS / 32), tb, 0, stream>>>(emis, emT, NS, NE);
  viterbi_fwd<<<512, 512, 0, stream>>>(obs, start, trans, emT, v, bp);
  viterbi_bt<<<NB, 64, 0, stream>>>(v, bp, path);
}